// Round 1
// 274.699 us; speedup vs baseline: 1.0481x; 1.0481x over previous
//
#include <hip/hip_runtime.h>
#include <hip/hip_fp16.h>

// APPNP encoder: e3 = ego + 0.9*A@(ego + 0.9*A@ego).
// R9: same 4-dispatch pipeline as R8, but bucket_scatter and sort_spmm1 move
// to 512-thread blocks. Both kernels are grid-limited (782 blocks = 3.05/CU)
// and latency-bound (VALUBusy 24%, HBM 30%, occupancy 23.6%); doubling waves
// per block raises waves/SIMD from ~3 to ~6 without touching the bucket
// geometry or ebuf layout.
//  1. conv_init: fp32 ego -> fp16 table; init padded bucket cursors
//  2. bucket_scatter (512t): single-pass scatter into padded bucket slots
//  3. sort_spmm1 (512t): per-bucket LDS counting sort -> row_start/row_end +
//     sorted ebuf, then spmm1 fused (edges L2-hot), writes e2 fp16
//  4. spmm2: pull SpMM from e2h -> fp32 out (nontemporal)

#define USER_NUM 60000
#define ITEM_NUM 40000
#define N_NODES  100000
#define EMB      64
#define NNZ      3200000
#define OMA      0.9f    // 1 - alpha
#define BR       128     // rows per bucket
#define NB       782     // ceil(100000/128)
#define TILE     4096    // edges per scatter block
#define CAPB     4480    // padded slots per bucket (mean 4096, +6 sigma)

typedef float f32x4 __attribute__((ext_vector_type(4)));

// ---- 1) fp32 split ego -> flat fp16 table; init bucket cursors ----------
__global__ __launch_bounds__(256) void conv_init(const float* __restrict__ ue,
                                                 const float* __restrict__ ie,
                                                 __half* __restrict__ dst,
                                                 int* __restrict__ bcursor) {
    int t = blockIdx.x * 256 + threadIdx.x;       // 8 floats per thread
    if (t < NB) bcursor[t] = t * CAPB;
    const int total8 = N_NODES * EMB / 8;         // 800,000
    if (t >= total8) return;
    size_t f0 = (size_t)t * 8;
    const size_t usz = (size_t)USER_NUM * EMB;    // 3,840,000 (mult of 8)
    const float4* s4 = (f0 < usz) ? (const float4*)(ue + f0)
                                  : (const float4*)(ie + (f0 - usz));
    float4 x = s4[0], y = s4[1];
    union { float4 f4; __half2 h2[4]; } o;
    o.h2[0] = __floats2half2_rn(x.x, x.y);
    o.h2[1] = __floats2half2_rn(x.z, x.w);
    o.h2[2] = __floats2half2_rn(y.x, y.y);
    o.h2[3] = __floats2half2_rn(y.z, y.w);
    ((float4*)dst)[t] = o.f4;
}

// ---- 2) single-pass bucket scatter into padded slots (512 threads) ------
// entry = (col | row_local<<17, val*0.9)
__global__ __launch_bounds__(512) void bucket_scatter(const int* __restrict__ rows,
                                                      const int* __restrict__ cols,
                                                      const float* __restrict__ vals,
                                                      int* __restrict__ bcursor,
                                                      int2* __restrict__ ebuf) {
    __shared__ int bins[NB + 1];   // hist, then exclusive offsets
    __shared__ int lcur[NB];       // binning cursors, then global write offsets
    __shared__ int wsum[8];
    __shared__ int2 stage[TILE];
    int t = threadIdx.x;
    int lane = t & 63, w = t >> 6;           // 8 waves
    for (int b = t; b <= NB; b += 512) bins[b] = 0;
    __syncthreads();

    // load edges, histogram into bins (8 edges/thread)
    int e0 = blockIdx.x * TILE;
    int mybk[8], mypk[8];
    float myv[8];
#pragma unroll
    for (int j = 0; j < 8; ++j) {
        int i = e0 + t + 512 * j;
        mybk[j] = -1;
        if (i < NNZ) {
            int r = rows[i], c = cols[i];
            myv[j]  = vals[i] * OMA;
            mybk[j] = r >> 7;
            mypk[j] = c | ((r & 127) << 17);
            atomicAdd(&bins[mybk[j]], 1);
        }
    }
    __syncthreads();

    // register scan: 2 bins/thread (covers 1024 >= 783), wave shfl scan +
    // cross-wave combine over 8 wave partials
    int b0 = t * 2;
    int r0 = (b0     < NB) ? bins[b0]     : 0;
    int r1 = (b0 + 1 < NB) ? bins[b0 + 1] : 0;
    int s = r0 + r1;
    int incl = s;
#pragma unroll
    for (int off = 1; off < 64; off <<= 1) {
        int v = __shfl_up(incl, off, 64);
        if (lane >= off) incl += v;
    }
    if (lane == 63) wsum[w] = incl;
    __syncthreads();
    int prefix = 0;
#pragma unroll
    for (int i = 0; i < 8; ++i) if (i < w) prefix += wsum[i];
    int excl = prefix + incl - s;
    if (b0     < NB) { bins[b0]     = excl; lcur[b0]     = excl; excl += r0; }
    if (b0 + 1 < NB) { bins[b0 + 1] = excl; lcur[b0 + 1] = excl; excl += r1; }
    if (t == 511) bins[NB] = prefix + incl;   // total valid edges this tile
    __syncthreads();

    // bin into stage (bucket-sorted order)
#pragma unroll
    for (int j = 0; j < 8; ++j) {
        if (mybk[j] >= 0) {
            int p = atomicAdd(&lcur[mybk[j]], 1);
            stage[p] = make_int2(mypk[j], __float_as_int(myv[j]));
        }
    }
    __syncthreads();

    // Phase A: reserve global runs; lcur[b] := global_base - local_start
    for (int b = t; b < NB; b += 512) {
        int st = bins[b], en = bins[b + 1];
        int cnt = en - st;
        if (cnt > 0) lcur[b] = atomicAdd(&bcursor[b], cnt) - st;
    }
    __syncthreads();

    // Phase B: lane-parallel coalesced flush (binary search bucket of entry i)
    int total = bins[NB];
    for (int i = t; i < total; i += 512) {
        int lo = 0, hi = NB;
        while (hi - lo > 1) {
            int mid = (lo + hi) >> 1;
            if (bins[mid] <= i) lo = mid; else hi = mid;
        }
        ebuf[(size_t)(lcur[lo] + i)] = stage[i];
    }
}

// ---- 3) per-bucket sort + fused spmm1 (512 threads) ---------------------
__global__ __launch_bounds__(512) void sort_spmm1(const int* __restrict__ bcursor,
                                                  int2* __restrict__ ebuf,
                                                  int* __restrict__ row_start,
                                                  int* __restrict__ row_end,
                                                  const __half* __restrict__ ego_h,
                                                  const float* __restrict__ ue,
                                                  const float* __restrict__ ie,
                                                  __half* __restrict__ e2h) {
    __shared__ int2 stage[CAPB];
    __shared__ int rhist[BR], rofs[BR], rcur[BR];
    int bk = blockIdx.x, t = threadIdx.x;
    int s = bk * CAPB;
    int cnt = min(bcursor[bk] - s, CAPB);

    if (t < BR) rhist[t] = 0;
    __syncthreads();
    for (int i = t; i < cnt; i += 512) {
        int2 v = ebuf[(size_t)(s + i)];
        stage[i] = v;
        atomicAdd(&rhist[(v.x >> 17) & 127], 1);
    }
    __syncthreads();
    if (t < 64) {   // wave-0 shfl scan over 128 bins (2 per lane)
        int h0 = rhist[2 * t], h1 = rhist[2 * t + 1];
        int pair = h0 + h1;
        int incl = pair;
#pragma unroll
        for (int off = 1; off < 64; off <<= 1) {
            int v = __shfl_up(incl, off, 64);
            if (t >= off) incl += v;
        }
        int base = incl - pair;
        rofs[2 * t]     = base;      rcur[2 * t]     = base;
        rofs[2 * t + 1] = base + h0; rcur[2 * t + 1] = base + h0;
    }
    __syncthreads();
    if (t < BR) {
        int r = (bk << 7) + t;
        if (r < N_NODES) {
            row_start[r] = s + rofs[t];
            row_end[r]   = s + rofs[t] + rhist[t];
        }
    }
    // write row-sorted edges back (L2-local region)
    for (int i = t; i < cnt; i += 512) {
        int2 v = stage[i];
        int p = atomicAdd(&rcur[(v.x >> 17) & 127], 1);
        ebuf[(size_t)(s + p)] = v;
    }
    __syncthreads();   // sorted edges visible block-wide (same CU L1/L2)

    // fused spmm1: 32 groups x 16 lanes; each group does 4 rows
    int lane  = t & 15;
    int qbase = (t & 63) & ~15;
    int g = t >> 4;                         // 0..31
    const float2* srcv = (const float2*)ego_h;
#pragma unroll
    for (int rr = 0; rr < 4; ++rr) {
        int rl = (g << 2) | rr;             // 0..127
        int r  = (bk << 7) + rl;
        if (r >= N_NODES) break;
        const float* egop = (r < USER_NUM) ? (ue + (size_t)r * EMB)
                                           : (ie + (size_t)(r - USER_NUM) * EMB);
        float4 acc = ((const float4*)egop)[lane];
        int ss = s + rofs[rl];
        int ee = ss + rhist[rl];
        int2 cv = (ss + lane < ee) ? ebuf[(size_t)(ss + lane)] : make_int2(0, 0);
        for (int k = ss; k < ee; k += 16) {
            int idxn = k + 16 + lane;
            int2 nv = (idxn < ee) ? ebuf[(size_t)idxn] : make_int2(0, 0);
#pragma unroll
            for (int j = 0; j < 16; ++j) {
                int   cj = __shfl(cv.x, qbase + j, 64) & 0x1FFFF;
                float vj = __int_as_float(__shfl(cv.y, qbase + j, 64));
                union { float2 f2; __half2 h2[2]; } u;
                u.f2 = srcv[(size_t)cj * 16 + lane];
                float2 a = __half22float2(u.h2[0]);
                float2 b = __half22float2(u.h2[1]);
                acc.x += vj * a.x; acc.y += vj * a.y;
                acc.z += vj * b.x; acc.w += vj * b.y;
            }
            cv = nv;
        }
        union { float2 f2; __half2 h2[2]; } o;
        o.h2[0] = __floats2half2_rn(acc.x, acc.y);
        o.h2[1] = __floats2half2_rn(acc.z, acc.w);
        ((float2*)e2h)[(size_t)r * 16 + lane] = o.f2;
    }
}

// ---- 4) spmm2: pull from e2h, fp32 nontemporal out ----------------------
__global__ __launch_bounds__(256) void spmm2(const int* __restrict__ row_start,
                                             const int* __restrict__ row_end,
                                             const int2* __restrict__ colval,
                                             const __half* __restrict__ src,
                                             const float* __restrict__ ue,
                                             const float* __restrict__ ie,
                                             float* __restrict__ outb) {
    int tid = blockIdx.x * 256 + threadIdx.x;
    int r = tid >> 4;
    if (r >= N_NODES) return;
    int lane  = threadIdx.x & 15;
    int qbase = (threadIdx.x & 63) & ~15;

    const float* egop = (r < USER_NUM) ? (ue + (size_t)r * EMB)
                                       : (ie + (size_t)(r - USER_NUM) * EMB);
    float4 acc = ((const float4*)egop)[lane];
    const float2* srcv = (const float2*)src;
    int s = row_start[r], e = row_end[r];

    int2 cv = (s + lane < e) ? colval[(size_t)(s + lane)] : make_int2(0, 0);
    for (int k = s; k < e; k += 16) {
        int idxn = k + 16 + lane;
        int2 nv = (idxn < e) ? colval[(size_t)idxn] : make_int2(0, 0);
#pragma unroll
        for (int j = 0; j < 16; ++j) {
            int   cj = __shfl(cv.x, qbase + j, 64) & 0x1FFFF;
            float vj = __int_as_float(__shfl(cv.y, qbase + j, 64));
            union { float2 f2; __half2 h2[2]; } u;
            u.f2 = srcv[(size_t)cj * 16 + lane];
            float2 a = __half22float2(u.h2[0]);
            float2 b = __half22float2(u.h2[1]);
            acc.x += vj * a.x; acc.y += vj * a.y;
            acc.z += vj * b.x; acc.w += vj * b.y;
        }
        cv = nv;
    }
    f32x4 av = { acc.x, acc.y, acc.z, acc.w };
    __builtin_nontemporal_store(av, &((f32x4*)outb)[(size_t)r * 16 + lane]);
}

// ---- launch -------------------------------------------------------------
extern "C" void kernel_launch(void* const* d_in, const int* in_sizes, int n_in,
                              void* d_out, int out_size, void* d_ws, size_t ws_size,
                              hipStream_t stream) {
    const int*   rows = (const int*)d_in[0];
    const int*   cols = (const int*)d_in[1];
    const float* vals = (const float*)d_in[2];
    const float* ue   = (const float*)d_in[3];
    const float* ie   = (const float*)d_in[4];
    float* out = (float*)d_out;

    char* ws = (char*)d_ws;
    __half* ego_h    = (__half*)ws;                   // 12,800,000 B
    __half* e2h      = (__half*)(ws + 12800000);      // 12,800,000 B
    int2*   ebuf     = (int2*)(ws + 25600000);        // 782*4480*8 = 28,026,880 B
    int*    row_s    = (int*)(ws + 53626880);         // 400,000 B
    int*    row_e    = (int*)(ws + 54026880);         // 400,000 B
    int*    bcursor  = (int*)(ws + 54426880);         // 3,128 B

    const int convBlocks = (N_NODES * EMB / 8 + 255) / 256;  // 3125
    conv_init<<<convBlocks, 256, 0, stream>>>(ue, ie, ego_h, bcursor);

    const int tiles = (NNZ + TILE - 1) / TILE;        // 782
    bucket_scatter<<<tiles, 512, 0, stream>>>(rows, cols, vals, bcursor, ebuf);
    sort_spmm1<<<NB, 512, 0, stream>>>(bcursor, ebuf, row_s, row_e, ego_h, ue, ie, e2h);

    const int spmmBlocks = (N_NODES * 16 + 255) / 256;  // 6250
    spmm2<<<spmmBlocks, 256, 0, stream>>>(row_s, row_e, ebuf, e2h, ue, ie, out);
}